// Round 5
// baseline (91.946 us; speedup 1.0000x reference)
//
#include <hip/hip_runtime.h>
#include <hip/hip_fp16.h>
#include <stdint.h>

// MultiResolutionHashEncoding, R5: two-pass, all-coalesced stores.
// Evidence R2-R4: all pipes <30% busy, TLP x2 -> +10%, ILP x2 -> +0%.
// Diagnosis: store-address divergence. out[b*16+level] across a wave = 64
// lines 128 B apart -> 33.5M store transactions (~54 us of TA work), invisible
// in WRITE_SIZE because L2/L3 merge partial lines. Fix: pass 1 stores
// ws[level][b] (consecutive lanes -> consecutive 4 B, half2), pass 2 is an
// LDS-tiled transpose with fully contiguous float4 output runs.

#define NUM_LEVELS 16
#define TABLE_SZ   16384
#define NCHUNK     32          // grid = 16 levels * 32 chunks = 512 blocks = 2/CU
#define BLOCK      512
#define TBLOCK     256

__constant__ float RESV[NUM_LEVELS] = {
    16.f, 22.f, 30.f, 42.f, 58.f, 80.f, 110.f, 152.f,
    210.f, 290.f, 400.f, 553.f, 763.f, 1053.f, 1453.f, 2005.f
};

struct PointCtx {
    uint32_t off[8];   // LDS byte offsets for 8 corners
    float    cw[8];    // trilinear corner weights
};

__device__ __forceinline__ void make_ctx(float px, float py, float pz, float r,
                                         PointCtx& c)
{
    // weights from UNSCALED position (faithful to reference)
    float wx = px - floorf(px);
    float wy = py - floorf(py);
    float wz = pz - floorf(pz);
    float ox = 1.f - wx, oy = 1.f - wy, oz = 1.f - wz;

    c.cw[0] = ox * oy * oz;
    c.cw[1] = wx * oy * oz;
    c.cw[2] = wx * wy * oz;
    c.cw[3] = ox * wy * oz;
    c.cw[4] = ox * oy * wz;
    c.cw[5] = wx * oy * wz;
    c.cw[6] = wx * wy * wz;
    c.cw[7] = ox * wy * wz;

    float sx = r * px, sy = r * py, sz = r * pz;
    // int32 wraparound hash == uint32 arithmetic; mask/shift distribute over
    // XOR -> per-component byte offsets (half2 = 4 B -> <<2).
    uint32_t mxl = ((uint32_t)(int)floorf(sx) & (TABLE_SZ - 1)) << 2;
    uint32_t mxh = ((uint32_t)(int)ceilf(sx)  & (TABLE_SZ - 1)) << 2;  // ceil, NOT lo+1
    uint32_t myl = ((2654435761u * (uint32_t)(int)floorf(sy)) & (TABLE_SZ - 1)) << 2;
    uint32_t myh = ((2654435761u * (uint32_t)(int)ceilf(sy))  & (TABLE_SZ - 1)) << 2;
    uint32_t mzl = ((805459861u  * (uint32_t)(int)floorf(sz)) & (TABLE_SZ - 1)) << 2;
    uint32_t mzh = ((805459861u  * (uint32_t)(int)ceilf(sz))  & (TABLE_SZ - 1)) << 2;

    c.off[0] = mxl ^ myl ^ mzl;
    c.off[1] = mxh ^ myl ^ mzl;
    c.off[2] = mxh ^ myh ^ mzl;
    c.off[3] = mxl ^ myh ^ mzl;
    c.off[4] = mxl ^ myl ^ mzh;
    c.off[5] = mxh ^ myl ^ mzh;
    c.off[6] = mxh ^ myh ^ mzh;
    c.off[7] = mxl ^ myh ^ mzh;
}

// mode 0: store half2 -> ws[level][b] (coalesced).  mode 1: direct float2 ->
// out[b*16+level] (fallback when ws too small; known store-divergent).
template<int MODE>
__global__ __launch_bounds__(BLOCK, 4)
void hashenc_lds_kernel(const float* __restrict__ x,
                        const float* __restrict__ tables,
                        __half2* __restrict__ ws,
                        float* __restrict__ out,
                        int B, int pts_per_block)
{
    __shared__ __half2 tab[TABLE_SZ];            // 64 KiB -> 2 blocks/CU

    const int level = blockIdx.x >> 5;           // blockIdx = level*NCHUNK + chunk
    const int chunk = blockIdx.x & (NCHUNK - 1);

    // ---- stage: global f32 table -> LDS f16 ----
    {
        const float4* __restrict__ gt4 =
            (const float4*)(tables + (size_t)level * (TABLE_SZ * 2));
        #pragma unroll
        for (int i = threadIdx.x; i < TABLE_SZ / 2; i += BLOCK) {
            float4 v = gt4[i];
            tab[2 * i]     = __floats2half2_rn(v.x, v.y);
            tab[2 * i + 1] = __floats2half2_rn(v.z, v.w);
        }
    }
    __syncthreads();

    const float r = RESV[level];
    const char* tb = (const char*)tab;
    __half2* wsl = ws + (size_t)level * B;

    int b = chunk * pts_per_block + threadIdx.x;
    const int pair_iters = pts_per_block / (2 * BLOCK);   // 8192/1024 = 8

    float pxA = x[3 * b + 0],           pyA = x[3 * b + 1],           pzA = x[3 * b + 2];
    float pxB = x[3 * (b + BLOCK) + 0], pyB = x[3 * (b + BLOCK) + 1], pzB = x[3 * (b + BLOCK) + 2];

    for (int k = 0; k < pair_iters; ++k) {
        float nxA = pxA, nyA = pyA, nzA = pzA;
        float nxB = pxB, nyB = pyB, nzB = pzB;
        int nb = b + 2 * BLOCK;
        if (k + 1 < pair_iters) {
            nxA = x[3 * nb + 0];             nyA = x[3 * nb + 1];             nzA = x[3 * nb + 2];
            nxB = x[3 * (nb + BLOCK) + 0];   nyB = x[3 * (nb + BLOCK) + 1];   nzB = x[3 * (nb + BLOCK) + 2];
        }

        PointCtx cA, cB;
        make_ctx(pxA, pyA, pzA, r, cA);
        make_ctx(pxB, pyB, pzB, r, cB);

        float2 fA[8], fB[8];
        #pragma unroll
        for (int c = 0; c < 8; ++c)
            fA[c] = __half22float2(*(const __half2*)(tb + cA.off[c]));
        #pragma unroll
        for (int c = 0; c < 8; ++c)
            fB[c] = __half22float2(*(const __half2*)(tb + cB.off[c]));

        float a0 = 0.f, a1 = 0.f, b0 = 0.f, b1 = 0.f;
        #pragma unroll
        for (int c = 0; c < 8; ++c) {
            a0 += fA[c].x * cA.cw[c];
            a1 += fA[c].y * cA.cw[c];
            b0 += fB[c].x * cB.cw[c];
            b1 += fB[c].y * cB.cw[c];
        }

        if (MODE == 0) {
            // coalesced: consecutive lanes -> consecutive 4 B
            wsl[b]         = __floats2half2_rn(a0, a1);
            wsl[b + BLOCK] = __floats2half2_rn(b0, b1);
        } else {
            ((float2*)out)[(size_t)b * NUM_LEVELS + level]           = make_float2(a0, a1);
            ((float2*)out)[(size_t)(b + BLOCK) * NUM_LEVELS + level] = make_float2(b0, b1);
        }

        pxA = nxA; pyA = nyA; pzA = nzA;
        pxB = nxB; pyB = nyB; pzB = nzB;
        b = nb;
    }
}

// Pass 2: ws[l][b] (half2) -> out[b][2l..2l+1] (f32), LDS-tiled so the global
// write is fully contiguous (64 lanes = 8 points x 8 float4 = 1024 B run).
__global__ __launch_bounds__(TBLOCK)
void transpose_kernel(const __half2* __restrict__ ws,
                      float* __restrict__ out, int B)
{
    __shared__ __half2 buf[TBLOCK][NUM_LEVELS + 1];   // +1 pad: stride 17 banks
    const int p0 = blockIdx.x * TBLOCK;
    const int t  = threadIdx.x;

    // read: for each level, consecutive lanes read consecutive points (coalesced)
    #pragma unroll
    for (int l = 0; l < NUM_LEVELS; ++l)
        buf[t][l] = ws[(size_t)l * B + p0 + t];
    __syncthreads();

    // write: 8 threads per point; thread j writes float4 j = levels (2j, 2j+1)
    const int pl = t >> 3;   // 0..31
    const int j  = t & 7;
    float4* o = (float4*)out;
    #pragma unroll
    for (int i = 0; i < 8; ++i) {         // 32 points per iteration
        int p = pl + i * 32;
        float2 f0 = __half22float2(buf[p][2 * j]);
        float2 f1 = __half22float2(buf[p][2 * j + 1]);
        o[(size_t)(p0 + p) * 8 + j] = make_float4(f0.x, f0.y, f1.x, f1.y);
    }
}

extern "C" void kernel_launch(void* const* d_in, const int* in_sizes, int n_in,
                              void* d_out, int out_size, void* d_ws, size_t ws_size,
                              hipStream_t stream) {
    const float* x      = (const float*)d_in[0];
    const float* tables = (const float*)d_in[1];
    float* out          = (float*)d_out;
    int B = in_sizes[0] / 3;                          // 262144
    int pts_per_block = (B + NCHUNK - 1) / NCHUNK;    // 8192
    dim3 grid(NUM_LEVELS * NCHUNK);

    size_t ws_needed = (size_t)NUM_LEVELS * B * sizeof(__half2);  // 16.8 MB
    if (ws_size >= ws_needed && (B % TBLOCK) == 0) {
        __half2* ws = (__half2*)d_ws;
        hashenc_lds_kernel<0><<<grid, BLOCK, 0, stream>>>(x, tables, ws, out, B, pts_per_block);
        transpose_kernel<<<dim3(B / TBLOCK), TBLOCK, 0, stream>>>(ws, out, B);
    } else {
        hashenc_lds_kernel<1><<<grid, BLOCK, 0, stream>>>(x, tables, nullptr, out, B, pts_per_block);
    }
}